// Round 2
// baseline (100.942 us; speedup 1.0000x reference)
//
#include <hip/hip_runtime.h>

// pose_estimate_loss: trilinear SDF sample of a (128,64,64) f32 grid at N=4.19M
// points + Huber(delta=1) mean.  Memory-bound on the 48 MiB point stream;
// voxel grid (2 MiB) lives in L2, so the 8 gathers/point are cache traffic.

constexpr int THREADS = 256;   // 4 waves/block
constexpr int BLOCKS  = 2048;  // 8 blocks/CU on 256 CUs; grid-stride covers N/4 groups

__global__ __launch_bounds__(THREADS) void sdf_partial_kernel(
    const float* __restrict__ voxels,    // [128][64][64]
    const float* __restrict__ pts,       // [N][3]
    const int*   __restrict__ hgt,       // scalar height_gt
    float* __restrict__ partials,        // [gridDim.x]
    int n)
{
    const float zoff = (float)hgt[0] * 0.5f;   // height_gt / 2.0
    const int tid    = blockIdx.x * THREADS + threadIdx.x;
    const int stride = gridDim.x * THREADS;
    const int ngroups = n >> 2;                // 4 points per group (N % 4 == 0)

    float acc = 0.0f;
    for (int g = tid; g < ngroups; g += stride) {
        // 4 points = 12 floats = 3 x float4 (48 B, 16 B-aligned), coalesced.
        const float4* p4 = reinterpret_cast<const float4*>(pts) + (size_t)g * 3;
        float4 A = p4[0];
        float4 B = p4[1];
        float4 C = p4[2];
        float px[4] = {A.x, A.w, B.z, C.y};
        float py[4] = {A.y, B.x, B.w, C.z};
        float pz[4] = {A.z, B.y, C.x, C.w};
#pragma unroll
        for (int i = 0; i < 4; ++i) {
            // shift to grid frame (LENGTH/2=6, WIDTH/2=3, height_gt/2)
            float x = px[i] + 6.0f;
            float y = py[i] + 3.0f;
            float z = pz[i] + zoff;
            // floor cell coords + fractional weights, matching reference f32 ops
            float xm = floorf(x / 0.1f);
            float ym = floorf(y / 0.1f);
            float zm = floorf(z / 0.1f);
            float ux = (x - xm * 0.1f) / 0.1f;
            float uy = (y - ym * 0.1f) / 0.1f;
            float uz = (z - zm * 0.1f) / 0.1f;
            // clamp AFTER frac, then truncate (values are >= 0 post-clamp)
            int x0 = (int)fminf(fmaxf(xm,        0.0f), 127.0f);
            int y0 = (int)fminf(fmaxf(ym,        0.0f),  63.0f);
            int z0 = (int)fminf(fmaxf(zm,        0.0f),  63.0f);
            int x1 = (int)fminf(fmaxf(xm + 1.0f, 0.0f), 127.0f);
            int y1 = (int)fminf(fmaxf(ym + 1.0f, 0.0f),  63.0f);
            int z1 = (int)fminf(fmaxf(zm + 1.0f, 0.0f),  63.0f);
            const int b00 = (x0 * 64 + y0) * 64;
            const int b01 = (x0 * 64 + y1) * 64;
            const int b10 = (x1 * 64 + y0) * 64;
            const int b11 = (x1 * 64 + y1) * 64;
            // 8-corner gather (L2-resident: grid is 2 MiB < 4 MiB/XCD)
            float v000 = voxels[b00 + z0];
            float v001 = voxels[b00 + z1];
            float v010 = voxels[b01 + z0];
            float v011 = voxels[b01 + z1];
            float v100 = voxels[b10 + z0];
            float v101 = voxels[b10 + z1];
            float v110 = voxels[b11 + z0];
            float v111 = voxels[b11 + z1];
            float wx1 = ux, wx0 = 1.0f - ux;
            float wy1 = uy, wy0 = 1.0f - uy;
            float wz1 = uz, wz0 = 1.0f - uz;
            float sdf =
                v111 * (wx1 * wy1 * wz1) + v110 * (wx1 * wy1 * wz0) +
                v101 * (wx1 * wy0 * wz1) + v100 * (wx1 * wy0 * wz0) +
                v011 * (wx0 * wy1 * wz1) + v010 * (wx0 * wy1 * wz0) +
                v001 * (wx0 * wy0 * wz1) + v000 * (wx0 * wy0 * wz0);
            // Huber, delta = 1
            float a = fabsf(sdf);
            acc += (a < 1.0f) ? 0.5f * sdf * sdf : (a - 0.5f);
        }
    }

    // wave (64-lane) shuffle reduce, then cross-wave LDS reduce
#pragma unroll
    for (int off = 32; off > 0; off >>= 1)
        acc += __shfl_down(acc, off);
    __shared__ float smem[THREADS / 64];
    if ((threadIdx.x & 63) == 0) smem[threadIdx.x >> 6] = acc;
    __syncthreads();
    if (threadIdx.x == 0) {
        float s = 0.0f;
#pragma unroll
        for (int w = 0; w < THREADS / 64; ++w) s += smem[w];
        partials[blockIdx.x] = s;
    }
}

// Deterministic final reduce: one block sums the per-block partials.
__global__ __launch_bounds__(THREADS) void reduce_kernel(
    const float* __restrict__ partials, float* __restrict__ out,
    int nparts, float inv_n)
{
    float acc = 0.0f;
    for (int i = threadIdx.x; i < nparts; i += THREADS) acc += partials[i];
#pragma unroll
    for (int off = 32; off > 0; off >>= 1)
        acc += __shfl_down(acc, off);
    __shared__ float smem[THREADS / 64];
    if ((threadIdx.x & 63) == 0) smem[threadIdx.x >> 6] = acc;
    __syncthreads();
    if (threadIdx.x == 0) {
        float s = 0.0f;
#pragma unroll
        for (int w = 0; w < THREADS / 64; ++w) s += smem[w];
        out[0] = s * inv_n;   // mean
    }
}

extern "C" void kernel_launch(void* const* d_in, const int* in_sizes, int n_in,
                              void* d_out, int out_size, void* d_ws, size_t ws_size,
                              hipStream_t stream) {
    const float* voxels = (const float*)d_in[0];   // (128,64,64) f32
    const float* pts    = (const float*)d_in[1];   // (N,3) f32
    const int*   hgt    = (const int*)d_in[2];     // scalar int
    float* out      = (float*)d_out;               // scalar f32 loss
    float* partials = (float*)d_ws;                // BLOCKS floats of scratch

    const int n = in_sizes[1] / 3;                 // 4,194,304

    sdf_partial_kernel<<<BLOCKS, THREADS, 0, stream>>>(voxels, pts, hgt, partials, n);
    reduce_kernel<<<1, THREADS, 0, stream>>>(partials, out, BLOCKS, 1.0f / (float)n);
}

// Round 5
// 40.434 us; speedup vs baseline: 2.4964x; 2.4964x over previous
//
#include <hip/hip_runtime.h>

// pose_estimate_loss: trilinear SDF sample of a (128,64,64) f32 grid at N=4.19M
// points + Huber(delta=1) mean.
//
// R3 post-mortem: quad table got 101->31.6us. Still split between gather
// transactions (2 lines/point) and VALU (6 f32 divides/point). R4: pack ALL
// 8 corners as 8x bf16 in ONE 16B entry -> 1 line-touch/point; replace x/0.1f
// and frac/0.1f with d=fma(p,10,off); u=d-floor(d)  (diff <= ~2e-5 in u,
// continuous fn -> negligible vs 2.9e-3 threshold).

constexpr int THREADS = 256;   // 4 waves/block
constexpr int BLOCKS  = 2048;  // 8 blocks/CU; grid-stride over N/4 groups
constexpr int TBL_ENTRIES = 128 * 64 * 64;            // 524,288 entries
constexpr size_t TBL_OFFSET = 16384;                  // partials live below
constexpr size_t WS_NEEDED  = TBL_OFFSET + (size_t)TBL_ENTRIES * 16;

__device__ __forceinline__ unsigned bf16rne(float f) {
    unsigned u = __float_as_uint(f);
    return (u + 0x7fffu + ((u >> 16) & 1u)) >> 16;    // round-nearest-even
}

// Build 8-corner bf16 table: entry(x,y,z) = corners (dx,dy,dz) with +1
// clamped per dim.  q.x=(000,001) q.y=(010,011) q.z=(100,101) q.w=(110,111),
// z-pair packed lo|hi<<16.  16B coalesced writes; reads are L1/L2-local.
__global__ __launch_bounds__(THREADS) void build_table_kernel(
    const float* __restrict__ v, uint4* __restrict__ t)
{
    int i  = blockIdx.x * THREADS + threadIdx.x;      // one thread per entry
    int z  = i & 63;
    int y  = (i >> 6) & 63;
    int x  = i >> 12;
    int dz = (z < 63) ? 1    : 0;
    int dy = (y < 63) ? 64   : 0;
    int dx = (x < 127) ? 4096 : 0;
    uint4 q;
    q.x = bf16rne(v[i])           | (bf16rne(v[i + dz])           << 16);
    q.y = bf16rne(v[i + dy])      | (bf16rne(v[i + dy + dz])      << 16);
    q.z = bf16rne(v[i + dx])      | (bf16rne(v[i + dx + dz])      << 16);
    q.w = bf16rne(v[i + dx + dy]) | (bf16rne(v[i + dx + dy + dz]) << 16);
    t[i] = q;
}

__device__ __forceinline__ float bflo(unsigned w) { return __uint_as_float(w << 16); }
__device__ __forceinline__ float bfhi(unsigned w) { return __uint_as_float(w & 0xffff0000u); }

// Main: ONE 16B gather per point.
__global__ __launch_bounds__(THREADS) void sdf_oct_kernel(
    const uint4* __restrict__ tbl,       // [128][64][64] 8-corner entries
    const float* __restrict__ pts,       // [N][3]
    const int*   __restrict__ hgt,       // scalar height_gt
    float* __restrict__ partials,        // [gridDim.x]
    int n)
{
    const float zsh = (float)hgt[0] * 0.5f * 10.0f;   // (height_gt/2)*10
    const int tid    = blockIdx.x * THREADS + threadIdx.x;
    const int stride = gridDim.x * THREADS;
    const int ngroups = n >> 2;

    float acc = 0.0f;
    for (int g = tid; g < ngroups; g += stride) {
        // 4 points = 12 floats = 3 x float4, coalesced 16B/lane
        const float4* p4 = reinterpret_cast<const float4*>(pts) + (size_t)g * 3;
        float4 A = p4[0];
        float4 B = p4[1];
        float4 C = p4[2];
        float px[4] = {A.x, A.w, B.z, C.y};
        float py[4] = {A.y, B.x, B.w, C.z};
        float pz[4] = {A.z, B.y, C.x, C.w};
#pragma unroll
        for (int i = 0; i < 4; ++i) {
            // grid-frame coords in cell units: (p + shift)/0.1 == p*10 + shift*10
            float dxc = fmaf(px[i], 10.0f, 60.0f);
            float dyc = fmaf(py[i], 10.0f, 30.0f);
            float dzc = fmaf(pz[i], 10.0f, zsh);
            float xm = floorf(dxc), ym = floorf(dyc), zm = floorf(dzc);
            float ux = dxc - xm, uy = dyc - ym, uz = dzc - zm;
            // pack hard-codes the clamped '+1' corner; low-side clamp (m<0)
            // collapses both ref corners to idx 0 == weight 0 on '+1' corner
            ux = (xm < 0.0f) ? 0.0f : ux;
            uy = (ym < 0.0f) ? 0.0f : uy;
            uz = (zm < 0.0f) ? 0.0f : uz;
            int ix = (int)fminf(fmaxf(xm, 0.0f), 127.0f);
            int iy = (int)fminf(fmaxf(ym, 0.0f),  63.0f);
            int iz = (int)fminf(fmaxf(zm, 0.0f),  63.0f);
            uint4 q = tbl[(ix << 12) + (iy << 6) + iz];
            // trilinear: lerp z, then y, then x
            float c000 = bflo(q.x), c001 = bfhi(q.x);
            float c010 = bflo(q.y), c011 = bfhi(q.y);
            float c100 = bflo(q.z), c101 = bfhi(q.z);
            float c110 = bflo(q.w), c111 = bfhi(q.w);
            float a00 = fmaf(uz, c001 - c000, c000);
            float a01 = fmaf(uz, c011 - c010, c010);
            float a10 = fmaf(uz, c101 - c100, c100);
            float a11 = fmaf(uz, c111 - c110, c110);
            float b0  = fmaf(uy, a01 - a00, a00);
            float b1  = fmaf(uy, a11 - a10, a10);
            float sdf = fmaf(ux, b1 - b0, b0);
            // Huber, delta = 1
            float a = fabsf(sdf);
            acc += (a < 1.0f) ? 0.5f * sdf * sdf : (a - 0.5f);
        }
    }

    // wave(64)-shuffle reduce + cross-wave LDS reduce
#pragma unroll
    for (int off = 32; off > 0; off >>= 1)
        acc += __shfl_down(acc, off);
    __shared__ float smem[THREADS / 64];
    if ((threadIdx.x & 63) == 0) smem[threadIdx.x >> 6] = acc;
    __syncthreads();
    if (threadIdx.x == 0) {
        float s = 0.0f;
#pragma unroll
        for (int w = 0; w < THREADS / 64; ++w) s += smem[w];
        partials[blockIdx.x] = s;
    }
}

// Fallback: direct 8-gather path (exact), used only if ws too small.
__global__ __launch_bounds__(THREADS) void sdf_direct_kernel(
    const float* __restrict__ voxels,
    const float* __restrict__ pts,
    const int*   __restrict__ hgt,
    float* __restrict__ partials,
    int n)
{
    const float zoff = (float)hgt[0] * 0.5f;
    const int tid    = blockIdx.x * THREADS + threadIdx.x;
    const int stride = gridDim.x * THREADS;
    const int ngroups = n >> 2;

    float acc = 0.0f;
    for (int g = tid; g < ngroups; g += stride) {
        const float4* p4 = reinterpret_cast<const float4*>(pts) + (size_t)g * 3;
        float4 A = p4[0];
        float4 B = p4[1];
        float4 C = p4[2];
        float px[4] = {A.x, A.w, B.z, C.y};
        float py[4] = {A.y, B.x, B.w, C.z};
        float pz[4] = {A.z, B.y, C.x, C.w};
#pragma unroll
        for (int i = 0; i < 4; ++i) {
            float x = px[i] + 6.0f;
            float y = py[i] + 3.0f;
            float z = pz[i] + zoff;
            float xm = floorf(x / 0.1f);
            float ym = floorf(y / 0.1f);
            float zm = floorf(z / 0.1f);
            float ux = (x - xm * 0.1f) / 0.1f;
            float uy = (y - ym * 0.1f) / 0.1f;
            float uz = (z - zm * 0.1f) / 0.1f;
            int x0 = (int)fminf(fmaxf(xm,        0.0f), 127.0f);
            int y0 = (int)fminf(fmaxf(ym,        0.0f),  63.0f);
            int z0 = (int)fminf(fmaxf(zm,        0.0f),  63.0f);
            int x1 = (int)fminf(fmaxf(xm + 1.0f, 0.0f), 127.0f);
            int y1 = (int)fminf(fmaxf(ym + 1.0f, 0.0f),  63.0f);
            int z1 = (int)fminf(fmaxf(zm + 1.0f, 0.0f),  63.0f);
            const int b00 = (x0 * 64 + y0) * 64;
            const int b01 = (x0 * 64 + y1) * 64;
            const int b10 = (x1 * 64 + y0) * 64;
            const int b11 = (x1 * 64 + y1) * 64;
            float v000 = voxels[b00 + z0];
            float v001 = voxels[b00 + z1];
            float v010 = voxels[b01 + z0];
            float v011 = voxels[b01 + z1];
            float v100 = voxels[b10 + z0];
            float v101 = voxels[b10 + z1];
            float v110 = voxels[b11 + z0];
            float v111 = voxels[b11 + z1];
            float wx1 = ux, wx0 = 1.0f - ux;
            float wy1 = uy, wy0 = 1.0f - uy;
            float wz1 = uz, wz0 = 1.0f - uz;
            float sdf =
                v111 * (wx1 * wy1 * wz1) + v110 * (wx1 * wy1 * wz0) +
                v101 * (wx1 * wy0 * wz1) + v100 * (wx1 * wy0 * wz0) +
                v011 * (wx0 * wy1 * wz1) + v010 * (wx0 * wy1 * wz0) +
                v001 * (wx0 * wy0 * wz1) + v000 * (wx0 * wy0 * wz0);
            float a = fabsf(sdf);
            acc += (a < 1.0f) ? 0.5f * sdf * sdf : (a - 0.5f);
        }
    }

#pragma unroll
    for (int off = 32; off > 0; off >>= 1)
        acc += __shfl_down(acc, off);
    __shared__ float smem[THREADS / 64];
    if ((threadIdx.x & 63) == 0) smem[threadIdx.x >> 6] = acc;
    __syncthreads();
    if (threadIdx.x == 0) {
        float s = 0.0f;
#pragma unroll
        for (int w = 0; w < THREADS / 64; ++w) s += smem[w];
        partials[blockIdx.x] = s;
    }
}

__global__ __launch_bounds__(THREADS) void reduce_kernel(
    const float* __restrict__ partials, float* __restrict__ out,
    int nparts, float inv_n)
{
    float acc = 0.0f;
    for (int i = threadIdx.x; i < nparts; i += THREADS) acc += partials[i];
#pragma unroll
    for (int off = 32; off > 0; off >>= 1)
        acc += __shfl_down(acc, off);
    __shared__ float smem[THREADS / 64];
    if ((threadIdx.x & 63) == 0) smem[threadIdx.x >> 6] = acc;
    __syncthreads();
    if (threadIdx.x == 0) {
        float s = 0.0f;
#pragma unroll
        for (int w = 0; w < THREADS / 64; ++w) s += smem[w];
        out[0] = s * inv_n;
    }
}

extern "C" void kernel_launch(void* const* d_in, const int* in_sizes, int n_in,
                              void* d_out, int out_size, void* d_ws, size_t ws_size,
                              hipStream_t stream) {
    const float* voxels = (const float*)d_in[0];   // (128,64,64) f32
    const float* pts    = (const float*)d_in[1];   // (N,3) f32
    const int*   hgt    = (const int*)d_in[2];     // scalar int
    float* out      = (float*)d_out;
    float* partials = (float*)d_ws;                // 2048 floats at ws head

    const int n = in_sizes[1] / 3;                 // 4,194,304

    if (ws_size >= WS_NEEDED) {
        uint4* tbl = (uint4*)((char*)d_ws + TBL_OFFSET);
        build_table_kernel<<<TBL_ENTRIES / THREADS, THREADS, 0, stream>>>(voxels, tbl);
        sdf_oct_kernel<<<BLOCKS, THREADS, 0, stream>>>(tbl, pts, hgt, partials, n);
    } else {
        sdf_direct_kernel<<<BLOCKS, THREADS, 0, stream>>>(voxels, pts, hgt, partials, n);
    }
    reduce_kernel<<<1, THREADS, 0, stream>>>(partials, out, BLOCKS, 1.0f / (float)n);
}